// Round 6
// baseline (570.582 us; speedup 1.0000x reference)
//
#include <hip/hip_runtime.h>

#define N_POINTS 1048576
#define FEAT 64
#define RES 256
#define PLANE_ELEMS (FEAT * RES * RES)  // elements per plane (4.19M)

// Spatial bucketing: 16 buckets/axis -> 4096 buckets, ~256 points each.
#define BUCKET_G 16
#define NBUCKET (BUCKET_G * BUCKET_G * BUCKET_G)  // 4096

// LDS-staged sample kernel: one block per bucket, 512 threads.
// Bucket footprint per plane: up to 18x18 texels (cells span ~16 texels + halo).
#define FOOT 18
#define FOOT2 (FOOT * FOOT)              // 324 texels
#define LDS_PLANE (FOOT2 * FEAT)         // 20736 fp16 elems = 41472 B
#define STAGE_U4 (3 * FOOT2 * FEAT / 8)  // 7776 uint4 loads (124416 B)

// Fused prep kernel: first TRANSPOSE_BLOCKS transpose, rest bucket-count.
#define TRANSPOSE_BLOCKS (3 * (RES * RES / 64))      // 3072
#define COUNT_BLOCKS (N_POINTS / 256)                // 4096
#define PREP_BLOCKS (TRANSPOSE_BLOCKS + COUNT_BLOCKS)

typedef unsigned short ushort_t;
typedef float v4f __attribute__((ext_vector_type(4)));       // native 16B vec
typedef _Float16 half8 __attribute__((ext_vector_type(8)));  // 8 fp16 = 16 B

// float -> fp16 bits (RTNE)
__device__ __forceinline__ ushort_t f2h(float f) {
  _Float16 h = (_Float16)f;
  return __builtin_bit_cast(unsigned short, h);
}

// ---------------------------------------------------------------------------
// Morton bucket helpers (4-bit per axis)
// ---------------------------------------------------------------------------
__device__ __forceinline__ unsigned part1by2(unsigned v) {
  v &= 0x3FFu;
  v = (v | (v << 16)) & 0x030000FFu;
  v = (v | (v << 8)) & 0x0300F00Fu;
  v = (v | (v << 4)) & 0x030C30C3u;
  v = (v | (v << 2)) & 0x09249249u;
  return v;
}

__device__ __forceinline__ unsigned compact1by2(unsigned v) {
  v &= 0x09249249u;
  v = (v | (v >> 2)) & 0x030C30C3u;
  v = (v | (v >> 4)) & 0x0300F00Fu;
  v = (v | (v >> 8)) & 0x030000FFu;
  v = (v | (v >> 16)) & 0x3FFu;
  return v;
}

__device__ __forceinline__ unsigned morton_bucket(float px, float py, float pz) {
  int bx = (int)((px + 1.0f) * (0.5f * BUCKET_G));
  int by = (int)((py + 1.0f) * (0.5f * BUCKET_G));
  int bz = (int)((pz + 1.0f) * (0.5f * BUCKET_G));
  bx = min(max(bx, 0), BUCKET_G - 1);
  by = min(max(by, 0), BUCKET_G - 1);
  bz = min(max(bz, 0), BUCKET_G - 1);
  return part1by2((unsigned)bx) | (part1by2((unsigned)by) << 1) |
         (part1by2((unsigned)bz) << 2);  // < 4096
}

// ---------------------------------------------------------------------------
// Fused prep: blocks [0,3072) transpose fp32 [C,H*W] -> flat fp16 [y][x][c];
// blocks [3072,7168) histogram the Morton buckets.
// ---------------------------------------------------------------------------
__global__ __launch_bounds__(256) void prep_transpose_count(
    const float* __restrict__ pxy, const float* __restrict__ pxz,
    const float* __restrict__ pyz, ushort_t* __restrict__ dst,
    const float* __restrict__ x, unsigned* __restrict__ hist) {
  const int b = blockIdx.x;
  const int tid = threadIdx.x;
  if (b >= TRANSPOSE_BLOCKS) {
    int n = (b - TRANSPOSE_BLOCKS) * 256 + tid;
    float px = x[n * 3 + 0];
    float py = x[n * 3 + 1];
    float pz = x[n * 3 + 2];
    atomicAdd(&hist[morton_bucket(px, py, pz)], 1u);
    return;
  }
  __shared__ ushort_t tile[64][72];  // [p][c], row = 144 B (16B-aligned)
  const int plane = b >> 10;                  // 0..2
  const int p0 = (b & 1023) * 64;
  const float* src = (plane == 0) ? pxy : ((plane == 1) ? pxz : pyz);
  ushort_t* out = dst + (size_t)plane * PLANE_ELEMS;
#pragma unroll
  for (int k = 0; k < 4; ++k) {
    int c = (tid >> 4) + k * 16;  // 0..63
    int pp = (tid & 15) * 4;      // 0..60, float4-aligned
    v4f v = __builtin_nontemporal_load(
        (const v4f*)(src + (size_t)c * (RES * RES) + p0 + pp));
    tile[pp + 0][c] = f2h(v.x);
    tile[pp + 1][c] = f2h(v.y);
    tile[pp + 2][c] = f2h(v.z);
    tile[pp + 3][c] = f2h(v.w);
  }
  __syncthreads();
#pragma unroll
  for (int k = 0; k < 2; ++k) {
    int idx = k * 256 + tid;
    int pp = idx >> 3;            // 0..63
    int c8 = (idx & 7) * 8;       // 0..56
    uint4 v = *(const uint4*)&tile[pp][c8];  // 16B-aligned LDS read
    *(uint4*)(out + (size_t)(p0 + pp) * FEAT + c8) = v;
  }
}

// Exclusive prefix sum over NBUCKET=4096 counts. One block of 1024 threads,
// 4 counts/thread (uint4) + Hillis-Steele block scan of the 1024 partials.
// Writes both starts[] (preserved) and cursor[] (consumed by scatter).
__global__ __launch_bounds__(1024) void scan_hist(
    const uint4* __restrict__ hist4, unsigned* __restrict__ starts,
    unsigned* __restrict__ cursor) {
  __shared__ unsigned part[1024];
  const int tid = threadIdx.x;
  uint4 h = hist4[tid];
  unsigned l0 = 0, l1 = h.x, l2 = h.x + h.y, l3 = h.x + h.y + h.z;
  unsigned s = l3 + h.w;
  part[tid] = s;
  __syncthreads();
  for (int off = 1; off < 1024; off <<= 1) {
    unsigned add = (tid >= off) ? part[tid - off] : 0u;
    __syncthreads();
    part[tid] += add;
    __syncthreads();
  }
  unsigned base = (tid == 0) ? 0u : part[tid - 1];
  uint4 o;
  o.x = base + l0;
  o.y = base + l1;
  o.z = base + l2;
  o.w = base + l3;
  ((uint4*)starts)[tid] = o;
  ((uint4*)cursor)[tid] = o;
}

// Scatter points into bucket-sorted order: xs[pos] = (px,py,pz, bitcast(n)).
__global__ __launch_bounds__(256) void bucket_scatter(
    const float* __restrict__ x, unsigned* __restrict__ cursor,
    float4* __restrict__ xs) {
  int n = blockIdx.x * 256 + threadIdx.x;
  float px = x[n * 3 + 0];
  float py = x[n * 3 + 1];
  float pz = x[n * 3 + 2];
  unsigned b = morton_bucket(px, py, pz);
  unsigned pos = atomicAdd(&cursor[b], 1u);
  xs[pos] = make_float4(px, py, pz, __uint_as_float((unsigned)n));
}

// ---------------------------------------------------------------------------
// LDS-staged sampling. One block = one bucket. Stage the bucket's 18x18
// footprint of all 3 planes into LDS (dense coalesced reads, no gathers),
// then sample every point of the bucket from LDS (ds_read_b128, 128-B texel
// rows span all 32 banks -> conflict-free). Math identical to reference.
// ---------------------------------------------------------------------------
__device__ __forceinline__ void plane_lds_ref(float u, float v, int rb, int cb,
                                              int c8, int* off, float* w) {
  float ix = fmaf(u, 0.5f * (float)(RES - 1), 0.5f * (float)(RES - 1));
  float iy = fmaf(v, 0.5f * (float)(RES - 1), 0.5f * (float)(RES - 1));
  float fx0 = floorf(ix), fy0 = floorf(iy);
  // weights from UNCLAMPED floor coords (reference semantics)
  float wx1 = ix - fx0, wy1 = iy - fy0;
  float wx0 = fx0 + 1.0f - ix, wy0 = fy0 + 1.0f - iy;
  int x0 = min(max((int)fx0, 0), RES - 1) - cb;      // local col in [0,17]
  int y0 = min(max((int)fy0, 0), RES - 1) - rb;      // local row in [0,17]
  int x1 = min(max((int)fx0 + 1, 0), RES - 1) - cb;
  int y1 = min(max((int)fy0 + 1, 0), RES - 1) - rb;
  off[0] = (y0 * FOOT + x0) * FEAT + c8;
  off[1] = (y0 * FOOT + x1) * FEAT + c8;
  off[2] = (y1 * FOOT + x0) * FEAT + c8;
  off[3] = (y1 * FOOT + x1) * FEAT + c8;
  w[0] = wx0 * wy0;
  w[1] = wx1 * wy0;
  w[2] = wx0 * wy1;
  w[3] = wx1 * wy1;
}

__device__ __forceinline__ void fma_mix8(half8 v, float w, float* acc) {
#pragma unroll
  for (int j = 0; j < 8; ++j) acc[j] = fmaf((float)v[j], w, acc[j]);
}

__global__ __launch_bounds__(512) void triplane_sample_lds(
    const float4* __restrict__ xs, const ushort_t* __restrict__ tps,
    const unsigned* __restrict__ starts, const unsigned* __restrict__ ends,
    float* __restrict__ out) {
  __shared__ __align__(16) ushort_t lds[3 * LDS_PLANE];  // 124416 B
  const int tid = threadIdx.x;
  const int bid = blockIdx.x;
  const int b = (bid & 7) * (NBUCKET / 8) + (bid >> 3);  // XCD swizzle
  const int bx = (int)compact1by2((unsigned)b);
  const int by = (int)compact1by2((unsigned)b >> 1);
  const int bz = (int)compact1by2((unsigned)b >> 2);
  // footprint bases: base = floor(bi * 255/16)
  const int xb = (255 * bx) >> 4;
  const int yb = (255 * by) >> 4;
  const int zb = (255 * bz) >> 4;

  // ---- stage: [plane][row][col][c] = global (clamped row/col) ----
  uint4* l4 = (uint4*)lds;
  for (int f = tid; f < STAGE_U4; f += 512) {
    int p = f / (FOOT2 * 8);                 // 0..2
    int rem = f - p * (FOOT2 * 8);
    int t = rem >> 3;                        // texel 0..323
    int sub = rem & 7;                       // 16-B chunk within texel
    int row = t / FOOT;
    int col = t - row * FOOT;
    int rb = (p == 0) ? yb : zb;             // rows: plane0=y, plane1/2=z
    int cb = (p == 2) ? yb : xb;             // cols: plane0/1=x, plane2=y
    int gr = min(rb + row, RES - 1);
    int gc = min(cb + col, RES - 1);
    l4[f] = *(const uint4*)(tps + (size_t)p * PLANE_ELEMS +
                            ((gr << 8) + gc) * FEAT + sub * 8);
  }
  __syncthreads();

  const unsigned s0 = starts[b], e0 = ends[b];
  const int c8 = (tid & 7) << 3;             // channel group base
  const ushort_t* l0 = lds;
  const ushort_t* l1 = lds + LDS_PLANE;
  const ushort_t* l2 = lds + 2 * LDS_PLANE;

  for (unsigned pid = s0 + (tid >> 3); pid < e0; pid += 64) {
    v4f pt = __builtin_nontemporal_load((const v4f*)xs + pid);
    unsigned n = __float_as_uint(pt.w);      // original point index

    int oa[4], ob[4], oc[4];
    float wa[4], wb[4], wc[4];
    plane_lds_ref(pt.x, pt.y, yb, xb, c8, oa, wa);  // xy: (x, y)
    plane_lds_ref(pt.x, pt.z, zb, xb, c8, ob, wb);  // xz: (x, z)
    plane_lds_ref(pt.y, pt.z, zb, yb, c8, oc, wc);  // yz: (y, z)

    // 12 LDS texel reads (ds_read_b128), then consume in reference order.
    const half8 a00 = *(const half8*)(l0 + oa[0]);
    const half8 a01 = *(const half8*)(l0 + oa[1]);
    const half8 a10 = *(const half8*)(l0 + oa[2]);
    const half8 a11 = *(const half8*)(l0 + oa[3]);
    const half8 b00 = *(const half8*)(l1 + ob[0]);
    const half8 b01 = *(const half8*)(l1 + ob[1]);
    const half8 b10 = *(const half8*)(l1 + ob[2]);
    const half8 b11 = *(const half8*)(l1 + ob[3]);
    const half8 c00 = *(const half8*)(l2 + oc[0]);
    const half8 c01 = *(const half8*)(l2 + oc[1]);
    const half8 c10 = *(const half8*)(l2 + oc[2]);
    const half8 c11 = *(const half8*)(l2 + oc[3]);

    float acc[8] = {0.f, 0.f, 0.f, 0.f, 0.f, 0.f, 0.f, 0.f};
    fma_mix8(a00, wa[0], acc);
    fma_mix8(a01, wa[1], acc);
    fma_mix8(a10, wa[2], acc);
    fma_mix8(a11, wa[3], acc);
    fma_mix8(b00, wb[0], acc);
    fma_mix8(b01, wb[1], acc);
    fma_mix8(b10, wb[2], acc);
    fma_mix8(b11, wb[3], acc);
    fma_mix8(c00, wc[0], acc);
    fma_mix8(c01, wc[1], acc);
    fma_mix8(c10, wc[2], acc);
    fma_mix8(c11, wc[3], acc);

    const float s = 1.0f / 3.0f;
    v4f lo = {acc[0] * s, acc[1] * s, acc[2] * s, acc[3] * s};
    v4f hi = {acc[4] * s, acc[5] * s, acc[6] * s, acc[7] * s};
    float* o = out + (size_t)n * FEAT + c8;
    __builtin_nontemporal_store(lo, (v4f*)o);
    __builtin_nontemporal_store(hi, (v4f*)(o + 4));
  }
}

// ---------------------------------------------------------------------------
// Unsorted fallback: ws fits fp16 atlas but not sort buffers. Flat atlas.
// ---------------------------------------------------------------------------
__global__ __launch_bounds__(256) void transpose_only(
    const float* __restrict__ pxy, const float* __restrict__ pxz,
    const float* __restrict__ pyz, ushort_t* __restrict__ dst) {
  __shared__ ushort_t tile[64][72];
  const int plane = blockIdx.y;
  const float* src = (plane == 0) ? pxy : ((plane == 1) ? pxz : pyz);
  ushort_t* out = dst + (size_t)plane * PLANE_ELEMS;
  const int p0 = blockIdx.x * 64;
  const int tid = threadIdx.x;
#pragma unroll
  for (int k = 0; k < 4; ++k) {
    int c = (tid >> 4) + k * 16;
    int pp = (tid & 15) * 4;
    v4f v = *(const v4f*)(src + (size_t)c * (RES * RES) + p0 + pp);
    tile[pp + 0][c] = f2h(v.x);
    tile[pp + 1][c] = f2h(v.y);
    tile[pp + 2][c] = f2h(v.z);
    tile[pp + 3][c] = f2h(v.w);
  }
  __syncthreads();
#pragma unroll
  for (int k = 0; k < 2; ++k) {
    int idx = k * 256 + tid;
    int pp = idx >> 3;
    int c8 = (idx & 7) * 8;
    uint4 v = *(const uint4*)&tile[pp][c8];
    *(uint4*)(out + (size_t)(p0 + pp) * FEAT + c8) = v;
  }
}

__device__ __forceinline__ void sample_plane_g(const ushort_t* __restrict__ tp,
                                               float u, float v, int c8,
                                               float* acc) {
  float ix = fmaf(u, 0.5f * (float)(RES - 1), 0.5f * (float)(RES - 1));
  float iy = fmaf(v, 0.5f * (float)(RES - 1), 0.5f * (float)(RES - 1));
  float fx0 = floorf(ix), fy0 = floorf(iy);
  float wx1 = ix - fx0, wy1 = iy - fy0;
  float wx0 = fx0 + 1.0f - ix, wy0 = fy0 + 1.0f - iy;
  int x0 = min(max((int)fx0, 0), RES - 1);
  int y0 = min(max((int)fy0, 0), RES - 1);
  int x1 = min(max((int)fx0 + 1, 0), RES - 1);
  int y1 = min(max((int)fy0 + 1, 0), RES - 1);
  const half8 v00 = *(const half8*)(tp + (size_t)(y0 * RES + x0) * FEAT + c8);
  const half8 v01 = *(const half8*)(tp + (size_t)(y0 * RES + x1) * FEAT + c8);
  const half8 v10 = *(const half8*)(tp + (size_t)(y1 * RES + x0) * FEAT + c8);
  const half8 v11 = *(const half8*)(tp + (size_t)(y1 * RES + x1) * FEAT + c8);
  fma_mix8(v00, wx0 * wy0, acc);
  fma_mix8(v01, wx1 * wy0, acc);
  fma_mix8(v10, wx0 * wy1, acc);
  fma_mix8(v11, wx1 * wy1, acc);
}

__global__ __launch_bounds__(256) void triplane_sample_f16(
    const float* __restrict__ x, const ushort_t* __restrict__ tps,
    float* __restrict__ out) {
  int t = blockIdx.x * 256 + threadIdx.x;
  int n = t >> 3;
  int c8 = (t & 7) << 3;
  float px = __builtin_nontemporal_load(x + n * 3 + 0);
  float py = __builtin_nontemporal_load(x + n * 3 + 1);
  float pz = __builtin_nontemporal_load(x + n * 3 + 2);
  float acc[8] = {0.f, 0.f, 0.f, 0.f, 0.f, 0.f, 0.f, 0.f};
  sample_plane_g(tps, px, py, c8, acc);
  sample_plane_g(tps + PLANE_ELEMS, px, pz, c8, acc);
  sample_plane_g(tps + 2 * PLANE_ELEMS, py, pz, c8, acc);
  const float s = 1.0f / 3.0f;
  v4f lo = {acc[0] * s, acc[1] * s, acc[2] * s, acc[3] * s};
  v4f hi = {acc[4] * s, acc[5] * s, acc[6] * s, acc[7] * s};
  float* o = out + (size_t)n * FEAT + c8;
  __builtin_nontemporal_store(lo, (v4f*)o);
  __builtin_nontemporal_store(hi, (v4f*)(o + 4));
}

// ---------------------------------------------------------------------------
// Last-resort fallback: direct gather from native [C,H,W] layout.
// ---------------------------------------------------------------------------
__device__ __forceinline__ float sample_one(const float* __restrict__ pc,
                                            float u, float v) {
  float ix = (u + 1.0f) * 0.5f * (float)(RES - 1);
  float iy = (v + 1.0f) * 0.5f * (float)(RES - 1);
  float fx0 = floorf(ix), fy0 = floorf(iy);
  float wx1 = ix - fx0, wy1 = iy - fy0;
  float wx0 = fx0 + 1.0f - ix, wy0 = fy0 + 1.0f - iy;
  int x0 = min(max((int)fx0, 0), RES - 1);
  int y0 = min(max((int)fy0, 0), RES - 1);
  int x1 = min(max((int)fx0 + 1, 0), RES - 1);
  int y1 = min(max((int)fy0 + 1, 0), RES - 1);
  return pc[y0 * RES + x0] * (wx0 * wy0) + pc[y0 * RES + x1] * (wx1 * wy0) +
         pc[y1 * RES + x0] * (wx0 * wy1) + pc[y1 * RES + x1] * (wx1 * wy1);
}

__global__ __launch_bounds__(256) void triplane_direct(
    const float* __restrict__ x, const float* __restrict__ pxy,
    const float* __restrict__ pxz, const float* __restrict__ pyz,
    float* __restrict__ out) {
  int t = blockIdx.x * 256 + threadIdx.x;
  int n = t >> 6;
  int c = t & 63;
  float px = x[n * 3 + 0];
  float py = x[n * 3 + 1];
  float pz = x[n * 3 + 2];
  const size_t cs = (size_t)c * (RES * RES);
  float acc = sample_one(pxy + cs, px, py) + sample_one(pxz + cs, px, pz) +
              sample_one(pyz + cs, py, pz);
  out[(size_t)n * FEAT + c] = acc * (1.0f / 3.0f);
}

extern "C" void kernel_launch(void* const* d_in, const int* in_sizes, int n_in,
                              void* d_out, int out_size, void* d_ws,
                              size_t ws_size, hipStream_t stream) {
  const float* x   = (const float*)d_in[0];
  const float* pxy = (const float*)d_in[1];
  const float* pxz = (const float*)d_in[2];
  const float* pyz = (const float*)d_in[3];
  float* out = (float*)d_out;

  const size_t tps_bytes = (size_t)3 * PLANE_ELEMS * sizeof(ushort_t);  // 24 MB
  const size_t xs_bytes  = (size_t)N_POINTS * sizeof(float4);           // 16 MB
  const size_t cnt_bytes = (size_t)NBUCKET * sizeof(unsigned);          // 16 KB
  const size_t need_sorted = tps_bytes + xs_bytes + 3 * cnt_bytes;

  if (ws_size >= need_sorted) {
    ushort_t* tps    = (ushort_t*)d_ws;
    float4* xs       = (float4*)((char*)d_ws + tps_bytes);
    unsigned* cursor = (unsigned*)((char*)d_ws + tps_bytes + xs_bytes);
    unsigned* hist   = cursor + NBUCKET;
    unsigned* starts = hist + NBUCKET;

    (void)hipMemsetAsync(hist, 0, cnt_bytes, stream);  // capturable
    prep_transpose_count<<<PREP_BLOCKS, 256, 0, stream>>>(pxy, pxz, pyz, tps,
                                                          x, hist);
    scan_hist<<<1, 1024, 0, stream>>>((const uint4*)hist, starts, cursor);
    bucket_scatter<<<N_POINTS / 256, 256, 0, stream>>>(x, cursor, xs);
    // after scatter, cursor[b] == end-of-bucket b
    triplane_sample_lds<<<NBUCKET, 512, 0, stream>>>(xs, tps, starts, cursor,
                                                     out);
  } else if (ws_size >= tps_bytes) {
    ushort_t* tps = (ushort_t*)d_ws;
    dim3 tgrid(RES * RES / 64, 3);
    transpose_only<<<tgrid, 256, 0, stream>>>(pxy, pxz, pyz, tps);
    triplane_sample_f16<<<(N_POINTS * 8) / 256, 256, 0, stream>>>(x, tps, out);
  } else {
    triplane_direct<<<(N_POINTS * 64) / 256, 256, 0, stream>>>(x, pxy, pxz,
                                                               pyz, out);
  }
}